// Round 4
// baseline (258.295 us; speedup 1.0000x reference)
//
#include <hip/hip_runtime.h>

#define BM 128
#define BN 128
#define BK 64

typedef __attribute__((ext_vector_type(8))) _Float16 half8;   // MFMA A/B frag
typedef __attribute__((ext_vector_type(2))) __fp16 h2raw;     // cvt_pkrtz result
typedef __attribute__((ext_vector_type(4))) float floatx4;    // MFMA C/D frag
typedef __attribute__((ext_vector_type(4))) float f4;         // raw float4

#define AS1U(p) ((const __attribute__((address_space(1))) unsigned int*)(p))
#define AS3U(p) ((__attribute__((address_space(3))) unsigned int*)(p))

// ---------- prepass: fp32 -> fp16 for x AND W in one dispatch ----------
__global__ __launch_bounds__(256) void cvt_fp32_fp16_2(
        const float* __restrict__ x, _Float16* __restrict__ xh, int nx8,
        const float* __restrict__ W, _Float16* __restrict__ wh, int nw8,
        int xblocks) {
    const f4* s4;
    half8* d8;
    int n8, i, stride;
    if ((int)blockIdx.x < xblocks) {
        s4 = (const f4*)x; d8 = (half8*)xh; n8 = nx8;
        i = blockIdx.x * blockDim.x + threadIdx.x;
        stride = xblocks * blockDim.x;
    } else {
        s4 = (const f4*)W; d8 = (half8*)wh; n8 = nw8;
        i = (blockIdx.x - xblocks) * blockDim.x + threadIdx.x;
        stride = (gridDim.x - xblocks) * blockDim.x;
    }
    union { h2raw h2[4]; half8 h8; } u;
    for (; i < n8; i += stride) {
        f4 a = s4[2 * i];
        f4 b = s4[2 * i + 1];
        u.h2[0] = __builtin_amdgcn_cvt_pkrtz(a.x, a.y);
        u.h2[1] = __builtin_amdgcn_cvt_pkrtz(a.z, a.w);
        u.h2[2] = __builtin_amdgcn_cvt_pkrtz(b.x, b.y);
        u.h2[3] = __builtin_amdgcn_cvt_pkrtz(b.z, b.w);
        d8[i] = u.h8;
    }
}

// ---------- fused fp16 GEMM + gumbel-sigmoid epilogue ----------
// C[m][n] = sum_k x[m][k]*W[n][k];  out = sigmoid((C + b + g1 - g2)/0.1)
// R0 K-loop (tiles 0..14 compiler-managed). Tile 15 hand-scheduled so the
// epilogue's u1/u2 register-prefetch (group 0) survives the staging wait
// (counted vmcnt(8) + raw barrier). Epilogue: barrier-free per-wave
// transpose, depth-2 pipelined u-loads, log-ratio math (one __logf saved,
// div->rcp). Device-safe intrinsics only: __logf/__expf/rcp.
__global__ __launch_bounds__(256, 3) void gumbel_fused(
        const _Float16* __restrict__ xh, const _Float16* __restrict__ wh,
        const float* __restrict__ bias, const float* __restrict__ u1,
        const float* __restrict__ u2, float* __restrict__ out,
        int M, int N, int K) {
    // K-loop: A tile 128x64 fp16 (16 KB) + B tile (16 KB).
    // Epilogue reuses as per-wave transpose buffers (4 x 1280 floats = 20 KB).
    __shared__ _Float16 Smem[2 * BM * BK];
    _Float16* As = Smem;
    _Float16* Bs = Smem + BM * BK;

    const int tid  = threadIdx.x;
    const int lane = tid & 63;
    const int wave = tid >> 6;

    // bid%8 == by%8 for all 8 sharers of an x row-panel -> same XCD L2.
    const int bid = blockIdx.x;
    const int by  = bid & (M / BM - 1);   // M/BM = 128 (pow2)
    const int bx  = bid >> 7;
    const int bm = by * BM;
    const int bn = bx * BN;

    // --- staging: tile = 1024 16B chunks (8 chunks per 64-fp16 row).
    // Swizzle on the GLOBAL side; LDS stays lane-ordered.
    int aoff[4], boff[4], lsoff[4];
#pragma unroll
    for (int rep = 0; rep < 4; rep++) {
        int s = wave * 64 + lane + rep * 256;
        int r = s >> 3;
        int cc = (s & 7) ^ (r & 7);
        aoff[rep] = (bm + r) * K + cc * 8;
        boff[rep] = (bn + r) * K + cc * 8;
        lsoff[rep] = s * 8;   // fp16-element offset
    }

    // --- fragment addressing (16x16x32: A[m=lane&15][k=(lane>>4)*8+j]) ---
    const int r16  = lane & 15;
    const int quad = lane >> 4;
    const int wm = (wave & 1) * 64;   // 2x2 wave grid, wave tile 64x64
    const int wn = (wave >> 1) * 64;

    floatx4 acc[4][4] = {};

    int aro[4][2], bro[4][2];
#pragma unroll
    for (int i = 0; i < 4; i++) {
        int ra = wm + i * 16 + r16;
        int rb = wn + i * 16 + r16;
#pragma unroll
        for (int s = 0; s < 2; s++) {
            aro[i][s] = ra * BK + (((s * 4 + quad) ^ (ra & 7)) * 8);
            bro[i][s] = rb * BK + (((s * 4 + quad) ^ (rb & 7)) * 8);
        }
    }

    // --- epilogue per-thread constants; bias hoisted to regs ---
    const int rrb = lane >> 3;            // 0..7
    const int chb = lane & 7;             // 0..7
    const int colA = bn + wn + chb * 4;
    const f4 bv0 = *(const f4*)(bias + colA);
    const f4 bv1 = *(const f4*)(bias + colA + 32);

#define NT_LOAD(p) __builtin_nontemporal_load((const f4*)(p))
    // u-prefetch: combo c = rep*2+rep2; row += 8*rep, col += 32*rep2
#define ISSUE(g, P) do { \
        int r0_ = (bm + wm + (g) * 16 + rrb) * N + colA; \
        P##v1[0] = NT_LOAD(u1 + r0_);              P##v2[0] = NT_LOAD(u2 + r0_); \
        P##v1[1] = NT_LOAD(u1 + r0_ + 32);         P##v2[1] = NT_LOAD(u2 + r0_ + 32); \
        P##v1[2] = NT_LOAD(u1 + r0_ + 8 * N);      P##v2[2] = NT_LOAD(u2 + r0_ + 8 * N); \
        P##v1[3] = NT_LOAD(u1 + r0_ + 8 * N + 32); P##v2[3] = NT_LOAD(u2 + r0_ + 8 * N + 32); \
    } while (0)

    f4 pAv1[4], pAv2[4], pBv1[4], pBv2[4];

    // ---------------- K-loop: tiles 0..14 (R0-verified structure) ----------
    for (int kb = 0; kb < K - BK; kb += BK) {
#pragma unroll
        for (int rep = 0; rep < 4; rep++) {
            __builtin_amdgcn_global_load_lds(AS1U(xh + aoff[rep] + kb), AS3U(As + lsoff[rep]), 16, 0, 0);
            __builtin_amdgcn_global_load_lds(AS1U(wh + boff[rep] + kb), AS3U(Bs + lsoff[rep]), 16, 0, 0);
        }
        __syncthreads();

#pragma unroll
        for (int s = 0; s < 2; s++) {
            half8 af[4], bf[4];
#pragma unroll
            for (int i = 0; i < 4; i++) {
                af[i] = *(const half8*)(As + aro[i][s]);
                bf[i] = *(const half8*)(Bs + bro[i][s]);
            }
#pragma unroll
            for (int i = 0; i < 4; i++) {
#pragma unroll
                for (int j = 0; j < 4; j++) {
                    acc[i][j] = __builtin_amdgcn_mfma_f32_16x16x32_f16(af[i], bf[j], acc[i][j], 0, 0, 0);
                }
            }
        }
        __syncthreads();
    }

    // ---------------- tile 15: hand-scheduled (counted wait) ----------------
    {
        const int kb = K - BK;
#pragma unroll
        for (int rep = 0; rep < 4; rep++) {
            __builtin_amdgcn_global_load_lds(AS1U(xh + aoff[rep] + kb), AS3U(As + lsoff[rep]), 16, 0, 0);
            __builtin_amdgcn_global_load_lds(AS1U(wh + boff[rep] + kb), AS3U(Bs + lsoff[rep]), 16, 0, 0);
        }
        __builtin_amdgcn_sched_barrier(0);
        ISSUE(0, pA);                     // 8 u-loads, newer than staging
        __builtin_amdgcn_sched_barrier(0);
        // drain the 8 staging loads only; leave the 8 u-loads in flight
        asm volatile("s_waitcnt vmcnt(8)" ::: "memory");
        __builtin_amdgcn_sched_barrier(0);
        __builtin_amdgcn_s_barrier();

#pragma unroll
        for (int s = 0; s < 2; s++) {
            half8 af[4], bf[4];
#pragma unroll
            for (int i = 0; i < 4; i++) {
                af[i] = *(const half8*)(As + aro[i][s]);
                bf[i] = *(const half8*)(Bs + bro[i][s]);
            }
#pragma unroll
            for (int i = 0; i < 4; i++) {
#pragma unroll
                for (int j = 0; j < 4; j++) {
                    acc[i][j] = __builtin_amdgcn_mfma_f32_16x16x32_f16(af[i], bf[j], acc[i][j], 0, 0, 0);
                }
            }
        }
        __builtin_amdgcn_sched_barrier(0);
        ISSUE(1, pB);
        __builtin_amdgcn_sched_barrier(0);
        // raw barrier: every wave's ds_reads retired before its arrival
        // (lgkm waits precede the MFMAs), so T may overwrite As/Bs after.
        __builtin_amdgcn_s_barrier();
    }

    // ---------------- epilogue: barrier-free, depth-2 pipelined ------------
    float* T = ((float*)Smem) + wave * 1280;
    const float inv_t = 10.0f;  // 1/TEMP

    // sigmoid((l + b + ln(ln v2 / ln v1))/0.1); ratio via rcp, sigmoid via rcp
#define GM1(OC, LC, BC, V1, V2) do { \
        float a1_ = __logf(V1); \
        float a2_ = __logf(V2); \
        float z_  = (LC + BC + __logf(a2_ * __builtin_amdgcn_rcpf(a1_))) * inv_t; \
        OC = __builtin_amdgcn_rcpf(1.0f + __expf(-z_)); \
    } while (0)

#define PROCESS(g, P) do { \
        /* prior group's T reads retired before overwriting (per-wave) */ \
        asm volatile("s_waitcnt lgkmcnt(0)" ::: "memory"); \
        __builtin_amdgcn_sched_barrier(0); \
        _Pragma("unroll") \
        for (int j = 0; j < 4; j++) { \
            int col = j * 16 + r16; \
            f4 v = {acc[g][j][0], acc[g][j][1], acc[g][j][2], acc[g][j][3]}; \
            *(f4*)(T + col * 20 + quad * 4) = v; \
        } \
        _Pragma("unroll") \
        for (int c = 0; c < 4; c++) { \
            int rr = rrb + (c >> 1) * 8; \
            int ch = chb + (c & 1) * 8; \
            f4 l4; \
            l4.x = T[(ch * 4 + 0) * 20 + rr]; \
            l4.y = T[(ch * 4 + 1) * 20 + rr]; \
            l4.z = T[(ch * 4 + 2) * 20 + rr]; \
            l4.w = T[(ch * 4 + 3) * 20 + rr]; \
            f4 bv = (c & 1) ? bv1 : bv0; \
            int idx = (bm + wm + (g) * 16 + rr) * N + bn + wn + ch * 4; \
            f4 o; \
            GM1(o.x, l4.x, bv.x, P##v1[c].x, P##v2[c].x); \
            GM1(o.y, l4.y, bv.y, P##v1[c].y, P##v2[c].y); \
            GM1(o.z, l4.z, bv.z, P##v1[c].z, P##v2[c].z); \
            GM1(o.w, l4.w, bv.w, P##v1[c].w, P##v2[c].w); \
            __builtin_nontemporal_store(o, (f4*)(out + idx)); \
        } \
    } while (0)

    PROCESS(0, pA);
    __builtin_amdgcn_sched_barrier(0);
    ISSUE(2, pA);                         // refill A after its reads
    __builtin_amdgcn_sched_barrier(0);
    PROCESS(1, pB);
    __builtin_amdgcn_sched_barrier(0);
    ISSUE(3, pB);
    __builtin_amdgcn_sched_barrier(0);
    PROCESS(2, pA);
    PROCESS(3, pB);

#undef PROCESS
#undef GM1
#undef ISSUE
#undef NT_LOAD
}

extern "C" void kernel_launch(void* const* d_in, const int* in_sizes, int n_in,
                              void* d_out, int out_size, void* d_ws, size_t ws_size,
                              hipStream_t stream) {
    const float* x  = (const float*)d_in[0];
    const float* u1 = (const float*)d_in[1];
    const float* u2 = (const float*)d_in[2];
    const float* W  = (const float*)d_in[3];
    const float* b  = (const float*)d_in[4];
    float* out = (float*)d_out;

    const int N = in_sizes[4];            // 1024
    const int K = in_sizes[3] / N;        // 1024
    const int M = in_sizes[0] / K;        // 16384

    _Float16* xh = (_Float16*)d_ws;
    _Float16* wh = xh + (size_t)M * K;

    const int xblocks = 2048, wblocks = 256;
    cvt_fp32_fp16_2<<<xblocks + wblocks, 256, 0, stream>>>(
        x, xh, (M * K) / 8, W, wh, (N * K) / 8, xblocks);

    dim3 grid((M / BM) * (N / BN));       // 128 * 8 = 1024
    gumbel_fused<<<grid, 256, 0, stream>>>(xh, wh, b, u1, u2, out, M, N, K);
}